// Round 9
// baseline (212.584 us; speedup 1.0000x reference)
//
#include <hip/hip_runtime.h>

#define MIN_V 1e-7f
#define MAX_V 10.0f
#define INV15 (1.0f/15.0f)
#define CAP 32

typedef _Float16 half2v __attribute__((ext_vector_type(2)));
typedef _Float16 half4v __attribute__((ext_vector_type(4)));
typedef _Float16 half8v __attribute__((ext_vector_type(8)));
typedef unsigned short ushort4v __attribute__((ext_vector_type(4)));

static __device__ __forceinline__ float clipv(float v){
    return fminf(fmaxf(v, MIN_V), MAX_V);
}
static __device__ __forceinline__ half2v shflx1(half2v v){
    int i = __builtin_bit_cast(int, v);
    i = __shfl_xor(i, 1, 64);
    return __builtin_bit_cast(half2v, i);
}

// Streaming pass: CH[i]=fp16(clip(H[i])) AND pre-fill lists with EZERO pattern
// (pad slots then point at the zeros row -> gather loops need no masking at all).
__global__ __launch_bounds__(256) void ch_fill(const float* __restrict__ H,
                                               _Float16* __restrict__ CH,
                                               unsigned* __restrict__ lists32,
                                               unsigned pat, int total8){
    int stride = gridDim.x*256;
    for (int i = blockIdx.x*256 + threadIdx.x; i < total8; i += stride){
        const float4* p = (const float4*)(H + (size_t)i*8);
        float4 a = p[0], b = p[1];
        half8v o;
        o[0]=(_Float16)clipv(a.x); o[1]=(_Float16)clipv(a.y);
        o[2]=(_Float16)clipv(a.z); o[3]=(_Float16)clipv(a.w);
        o[4]=(_Float16)clipv(b.x); o[5]=(_Float16)clipv(b.y);
        o[6]=(_Float16)clipv(b.z); o[7]=(_Float16)clipv(b.w);
        *(half8v*)(CH + (size_t)i*8) = o;
        lists32[i] = pat;                 // total32 == total8 == N*CAP/2
    }
}

// node -> edge incidence lists (ushort edge ids; one 64B line per node)
__global__ void build_lists(const int* __restrict__ edges, int* __restrict__ cnt,
                            unsigned short* __restrict__ lists, int total){
    int i = blockIdx.x*256 + threadIdx.x;
    if (i >= total) return;
    int node = edges[i];
    int p = atomicAdd(&cnt[node], 1);
    if (p < CAP) lists[(size_t)node*CAP + p] = (unsigned short)(i >> 4);
}

// ES1s[e][d] = (1/15) * sum_s CH[idx_s][d]^2, fp16.
// 16 lanes per edge; node ids via DIRECT broadcast loads (no bpermute chain):
// all 16 idx loads are independent -> 16 gathers in flight.
__global__ __launch_bounds__(256) void es_l1(const _Float16* __restrict__ CH,
                                             const int* __restrict__ edges,
                                             _Float16* __restrict__ ES1s, int E){
    int tid = threadIdx.x;
    int sub = tid & 15;
    int e = blockIdx.x*16 + (tid >> 4);
    if (e >= E) return;
    const int* row = edges + (size_t)e*16;
    float s[8];
    #pragma unroll
    for (int j=0;j<8;++j) s[j] = 0.f;
    #pragma unroll
    for (int t=0;t<16;++t){
        int idx = row[t];                  // uniform within 16-group -> HW broadcast
        half8v v = *(const half8v*)(CH + (size_t)idx*128 + sub*8);
        #pragma unroll
        for (int j=0;j<8;++j){ float f = (float)v[j]; s[j] += f*f; }
    }
    half8v o;
    #pragma unroll
    for (int j=0;j<8;++j) o[j] = (_Float16)(s[j]*INV15);
    *(half8v*)(ES1s + (size_t)e*128 + sub*8) = o;
}

// Fused layer-1, PERSISTENT blocks: gather (half-wave/node, unroll-4,
// pre-padded lists -> maskless, ONE ushort4 broadcast list-load per trip,
// zero bpermutes) -> double-buffered LDS -> dot2 gemm (b128 LDS reads).
__global__ __launch_bounds__(256) void fused_l1(
    const _Float16* __restrict__ CH, const _Float16* __restrict__ ES1s,
    const int* __restrict__ cnt, const unsigned short* __restrict__ lists,
    const float* __restrict__ W1, const float* __restrict__ b1,
    _Float16* __restrict__ X, int N){
    __shared__ _Float16 snw[2][8*128];
    int tid = threadIdx.x;
    int wave = tid >> 6, lane = tid & 63;

    int q = lane >> 4, h = lane & 15;
    half2v w2[16];
    #pragma unroll
    for (int i=0;i<16;++i){
        w2[i][0] = (_Float16)W1[(q*32+2*i  )*16 + h];
        w2[i][1] = (_Float16)W1[(q*32+2*i+1)*16 + h];
    }
    const half2v ones = {(_Float16)1.f, (_Float16)1.f};
    float bv = b1[h];

    int hw = tid >> 5;        // half-wave id 0..7
    int k32 = tid & 31;
    int dq = k32 * 4;

    const _Float16 i15 = (_Float16)INV15;
    const half4v i15v = {i15, i15, i15, i15};
    const half4v z4 = {(_Float16)0.f,(_Float16)0.f,(_Float16)0.f,(_Float16)0.f};

    int nchunks = (N + 7) >> 3;
    int parity = 0;
    for (int chunk = blockIdx.x; chunk < nchunks; chunk += gridDim.x, parity ^= 1){
        int nb = chunk * 8;
        _Float16* sbuf = &snw[parity][0];

        // ---- phase 1: gather node nb+hw ----
        int n = nb + hw;
        if (n < N){
            int len = cnt[n]; if (len > CAP) len = CAP;
            const unsigned short* lrow = lists + (size_t)n*CAP;

            half4v hv = *(const half4v*)(CH + (size_t)n*128 + dq);
            half4v p16 = (hv * hv) * i15v;

            float a0=0.f, a1=0.f, a2=0.f, a3=0.f;
            for (int k0=0;k0<len;k0+=4){
                ushort4v e4 = *(const ushort4v*)(lrow + k0);   // 8-B broadcast load
                half4v v0 = *(const half4v*)(ES1s + (size_t)e4[0]*128 + dq);
                half4v v1 = *(const half4v*)(ES1s + (size_t)e4[1]*128 + dq);
                half4v v2 = *(const half4v*)(ES1s + (size_t)e4[2]*128 + dq);
                half4v v3 = *(const half4v*)(ES1s + (size_t)e4[3]*128 + dq);
                half4v s0 = __builtin_elementwise_sqrt(__builtin_elementwise_max(v0 - p16, z4));
                half4v s1 = __builtin_elementwise_sqrt(__builtin_elementwise_max(v1 - p16, z4));
                half4v s2 = __builtin_elementwise_sqrt(__builtin_elementwise_max(v2 - p16, z4));
                half4v s3 = __builtin_elementwise_sqrt(__builtin_elementwise_max(v3 - p16, z4));
                a0 += ((float)s0[0] + (float)s1[0]) + ((float)s2[0] + (float)s3[0]);
                a1 += ((float)s0[1] + (float)s1[1]) + ((float)s2[1] + (float)s3[1]);
                a2 += ((float)s0[2] + (float)s1[2]) + ((float)s2[2] + (float)s3[2]);
                a3 += ((float)s0[3] + (float)s1[3]) + ((float)s2[3] + (float)s3[3]);
            }
            half4v o;
            o[0] = (_Float16)((float)hv[0] + a0);
            o[1] = (_Float16)((float)hv[1] + a1);
            o[2] = (_Float16)((float)hv[2] + a2);
            o[3] = (_Float16)((float)hv[3] + a3);
            *(half4v*)&sbuf[hw*128 + dq] = o;
        }
        __syncthreads();

        // ---- phase 2: wave handles nodes nb+wave*2 .. +1, dot2 gemm ----
        #pragma unroll
        for (int r=0;r<2;++r){
            int nl = wave*2 + r;
            int n2 = nb + nl;
            if (n2 >= N) continue;
            float acc = 0.f, rs = 0.f;
            #pragma unroll
            for (int j=0;j<4;++j){
                half8v v = *(const half8v*)&sbuf[nl*128 + q*32 + j*8];
                half2v p0 = {v[0],v[1]}, p1 = {v[2],v[3]}, p2 = {v[4],v[5]}, p3 = {v[6],v[7]};
                acc = __builtin_amdgcn_fdot2(p0, w2[j*4+0], acc, false);
                acc = __builtin_amdgcn_fdot2(p1, w2[j*4+1], acc, false);
                acc = __builtin_amdgcn_fdot2(p2, w2[j*4+2], acc, false);
                acc = __builtin_amdgcn_fdot2(p3, w2[j*4+3], acc, false);
                rs  = __builtin_amdgcn_fdot2(p0, ones, rs, false);
                rs  = __builtin_amdgcn_fdot2(p1, ones, rs, false);
                rs  = __builtin_amdgcn_fdot2(p2, ones, rs, false);
                rs  = __builtin_amdgcn_fdot2(p3, ones, rs, false);
            }
            acc += __shfl_xor(acc, 16, 64);
            rs  += __shfl_xor(rs , 16, 64);
            acc += __shfl_xor(acc, 32, 64);
            rs  += __shfl_xor(rs , 32, 64);
            if (q == 0){
                float o = acc * __builtin_amdgcn_rcpf(rs) + bv;
                X[(size_t)n2*16 + h] = (_Float16)fmaxf(o, 0.f);
            }
        }
        // double-buffered LDS: next chunk's barrier orders phase2 before rewrite
    }
}

// ES2s[e][d] = (1/15) * sum_s clipfloor(X[idx_s][d])^2, fp16. Thread = (edge, 4 dims).
__global__ __launch_bounds__(256) void es_l2(const _Float16* __restrict__ X,
                                             const int* __restrict__ edges,
                                             _Float16* __restrict__ ES2s, int E){
    int t = blockIdx.x*256 + threadIdx.x;
    int e = t >> 2, dq = (t & 3)*4;
    if (e >= E) return;
    const int* row = edges + (size_t)e*16;
    const _Float16 c7 = (_Float16)1e-7f;
    const half4v c7v = {c7, c7, c7, c7};
    float s0=0.f, s1=0.f, s2=0.f, s3=0.f;
    #pragma unroll
    for (int s=0;s<16;++s){
        half4v v = *(const half4v*)(X + (size_t)row[s]*16 + dq);
        v = __builtin_elementwise_max(v, c7v);
        float f0=(float)v[0], f1=(float)v[1], f2=(float)v[2], f3=(float)v[3];
        s0 += f0*f0; s1 += f1*f1; s2 += f2*f2; s3 += f3*f3;
    }
    half4v o;
    o[0]=(_Float16)(s0*INV15); o[1]=(_Float16)(s1*INV15);
    o[2]=(_Float16)(s2*INV15); o[3]=(_Float16)(s3*INV15);
    *(half4v*)(ES2s + (size_t)e*16 + dq) = o;
}

// Layer-2 node update: TWO threads per node; lists pre-padded -> maskless
// unconditional unroll-4 loads; dot2 gemm with f16 W2 pairs in LDS.
__global__ __launch_bounds__(256) void node_l2(
    const _Float16* __restrict__ X, const _Float16* __restrict__ ES2s,
    const int* __restrict__ cnt, const unsigned short* __restrict__ lists,
    const float* __restrict__ W2, const float* __restrict__ b2,
    float* __restrict__ out, int N){
    __shared__ half2v sW2h[8*40];
    __shared__ float sb[40];
    for (int i=threadIdx.x;i<320;i+=256){
        int d2 = i/40, c = i - d2*40;
        half2v wp;
        wp[0] = (_Float16)W2[(2*d2  )*40 + c];
        wp[1] = (_Float16)W2[(2*d2+1)*40 + c];
        sW2h[i] = wp;
    }
    if (threadIdx.x < 40) sb[threadIdx.x] = b2[threadIdx.x];
    __syncthreads();
    int t = blockIdx.x*256 + threadIdx.x;
    int n = t >> 1, p = t & 1;
    if (n >= N) return;

    const _Float16 c7 = (_Float16)1e-7f;
    const half8v c7v = {c7,c7,c7,c7,c7,c7,c7,c7};
    const half8v z8 = {(_Float16)0.f,(_Float16)0.f,(_Float16)0.f,(_Float16)0.f,
                       (_Float16)0.f,(_Float16)0.f,(_Float16)0.f,(_Float16)0.f};
    const _Float16 i15 = (_Float16)INV15;
    const half8v i15v = {i15,i15,i15,i15,i15,i15,i15,i15};

    half8v xh = *(const half8v*)(X + (size_t)n*16 + p*8);
    xh = __builtin_elementwise_max(xh, c7v);
    half8v ps = (xh*xh)*i15v;

    float xc[8], ad[8];
    #pragma unroll
    for (int d=0;d<8;++d){ xc[d]=(float)xh[d]; ad[d]=0.f; }

    int len = cnt[n]; if (len > CAP) len = CAP;
    const unsigned short* lrow = lists + (size_t)n*CAP;
    for (int k0=0;k0<len;k0+=4){
        ushort4v e4 = *(const ushort4v*)(lrow + k0);   // pads hold E -> zeros row
        half8v r0 = *(const half8v*)(ES2s + (size_t)e4[0]*16 + p*8);
        half8v r1 = *(const half8v*)(ES2s + (size_t)e4[1]*16 + p*8);
        half8v r2 = *(const half8v*)(ES2s + (size_t)e4[2]*16 + p*8);
        half8v r3 = *(const half8v*)(ES2s + (size_t)e4[3]*16 + p*8);
        half8v s0 = __builtin_elementwise_sqrt(__builtin_elementwise_max(r0-ps, z8));
        half8v s1 = __builtin_elementwise_sqrt(__builtin_elementwise_max(r1-ps, z8));
        half8v s2 = __builtin_elementwise_sqrt(__builtin_elementwise_max(r2-ps, z8));
        half8v s3 = __builtin_elementwise_sqrt(__builtin_elementwise_max(r3-ps, z8));
        #pragma unroll
        for (int d=0;d<8;++d)
            ad[d] += ((float)s0[d] + (float)s1[d]) + ((float)s2[d] + (float)s3[d]);
    }
    float rsl = 0.f;
    float nw[8];
    #pragma unroll
    for (int d=0;d<8;++d){ nw[d] = xc[d] + ad[d]; rsl += nw[d]; }
    float rs = rsl + __shfl_xor(rsl, 1, 64);
    float rinv = __builtin_amdgcn_rcpf(rs);

    half2v mine[4], oth[4];
    #pragma unroll
    for (int i=0;i<4;++i){
        mine[i][0] = (_Float16)nw[2*i];
        mine[i][1] = (_Float16)nw[2*i+1];
        oth[i] = shflx1(mine[i]);
    }
    half2v all8[8];
    #pragma unroll
    for (int i=0;i<4;++i){
        all8[4*p + i]     = mine[i];
        all8[4*(1-p) + i] = oth[i];
    }

    float ob[20];
    #pragma unroll
    for (int c=0;c<20;++c){
        int col = p*20 + c;
        float acc = 0.f;
        #pragma unroll
        for (int d2=0;d2<8;++d2)
            acc = __builtin_amdgcn_fdot2(all8[d2], sW2h[d2*40+col], acc, false);
        ob[c] = rinv*acc + sb[col];
    }
    float4* op = (float4*)(out + (size_t)n*40 + p*20);
    #pragma unroll
    for (int j=0;j<5;++j) op[j] = ((float4*)ob)[j];
}

extern "C" void kernel_launch(void* const* d_in, const int* in_sizes, int n_in,
                              void* d_out, int out_size, void* d_ws, size_t ws_size,
                              hipStream_t stream){
    (void)n_in; (void)out_size; (void)ws_size;
    const float* H  = (const float*)d_in[0];
    const float* W1 = (const float*)d_in[1];
    const float* b1 = (const float*)d_in[2];
    const float* W2 = (const float*)d_in[3];
    const float* b2 = (const float*)d_in[4];
    const int* edges = (const int*)d_in[5];
    float* out = (float*)d_out;

    const int N = in_sizes[0] / 128;   // 200000
    const int E = in_sizes[5] / 16;    // 40000
    const int total = E * 16;          // 640000
    const int total8 = N * 128 / 8;    // 3.2M  (== N*CAP/2, the lists u32 count)

    char* ws = (char*)d_ws;
    size_t off = 0;
    // region A: CH (dead after fused_l1) -> reused for ES2s
    _Float16* CH   = (_Float16*)(ws + off);
    _Float16* ES2s = (_Float16*)(ws + off);                 // (E+1) rows x 32 B = 1.28 MB
    off += (size_t)N*128*sizeof(_Float16);                  // 51.20 MB
    _Float16* ES1s = (_Float16*)(ws + off); off += (size_t)(E+1)*128*sizeof(_Float16); // 10.24 MB
    _Float16* X    = (_Float16*)(ws + off); off += (size_t)N*16*sizeof(_Float16);      //  6.40 MB
    int* cnt = (int*)(ws + off); off += (size_t)N*sizeof(int);                         //  0.80 MB
    unsigned short* lists = (unsigned short*)(ws + off);
    off += (size_t)N*CAP*sizeof(unsigned short);                                       // 12.80 MB

    unsigned pat = (unsigned)E | ((unsigned)E << 16);
    hipMemsetAsync(cnt, 0, (size_t)N*sizeof(int), stream);
    hipMemsetAsync(ES1s + (size_t)E*128, 0, 128*sizeof(_Float16), stream);  // zeros row
    ch_fill<<<2048, 256, 0, stream>>>(H, CH, (unsigned*)lists, pat, total8);
    build_lists<<<(total+255)/256, 256, 0, stream>>>(edges, cnt, lists, total);
    es_l1<<<(E+15)/16, 256, 0, stream>>>(CH, edges, ES1s, E);
    fused_l1<<<2048, 256, 0, stream>>>(CH, ES1s, cnt, lists, W1, b1, X, N);
    // CH dead from here; ES2s may now overwrite region A
    hipMemsetAsync(ES2s + (size_t)E*16, 0, 16*sizeof(_Float16), stream);    // zeros row
    es_l2<<<(E*4+255)/256, 256, 0, stream>>>(X, edges, ES2s, E);
    node_l2<<<(N*2+255)/256, 256, 0, stream>>>(X, ES2s, cnt, lists, W2, b2, out, N);
}

// Round 10
// 210.085 us; speedup vs baseline: 1.0119x; 1.0119x over previous
//
#include <hip/hip_runtime.h>

#define MIN_V 1e-7f
#define MAX_V 10.0f
#define INV15 (1.0f/15.0f)
#define CAP 32

typedef _Float16 half2v __attribute__((ext_vector_type(2)));
typedef _Float16 half4v __attribute__((ext_vector_type(4)));
typedef _Float16 half8v __attribute__((ext_vector_type(8)));

static __device__ __forceinline__ float clipv(float v){
    return fminf(fmaxf(v, MIN_V), MAX_V);
}
static __device__ __forceinline__ float rsqrt_arg(float v){   // sqrt(max(v,0)), raw HW sqrt
    return __builtin_amdgcn_sqrtf(fmaxf(v, 0.f));
}

// Pure streaming pass: CH[i] = fp16(clip(H[i])), grid-stride, 8 elems/thread/iter
__global__ __launch_bounds__(256) void ch_stream(const float* __restrict__ H,
                                                 _Float16* __restrict__ CH, int total8){
    int stride = gridDim.x*256;
    for (int i = blockIdx.x*256 + threadIdx.x; i < total8; i += stride){
        const float4* p = (const float4*)(H + (size_t)i*8);
        float4 a = p[0], b = p[1];
        half8v o;
        o[0]=(_Float16)clipv(a.x); o[1]=(_Float16)clipv(a.y);
        o[2]=(_Float16)clipv(a.z); o[3]=(_Float16)clipv(a.w);
        o[4]=(_Float16)clipv(b.x); o[5]=(_Float16)clipv(b.y);
        o[6]=(_Float16)clipv(b.z); o[7]=(_Float16)clipv(b.w);
        *(half8v*)(CH + (size_t)i*8) = o;
    }
}

// node -> edge incidence lists (ushort edge ids; one 64B line per node)
__global__ void build_lists(const int* __restrict__ edges, int* __restrict__ cnt,
                            unsigned short* __restrict__ lists, int total){
    int i = blockIdx.x*256 + threadIdx.x;
    if (i >= total) return;
    int node = edges[i];
    int p = atomicAdd(&cnt[node], 1);
    if (p < CAP) lists[(size_t)node*CAP + p] = (unsigned short)(i >> 4);
}

// ES1s[e][d] = (1/15) * sum_s CH[idx_s][d]^2, fp16. Wave per edge, lane = 2 dims.
// Node ids preloaded one-per-lane and broadcast via shfl -> all 16 gathers independent.
// (R5's version — best measured ensemble.)
__global__ __launch_bounds__(256) void es_l1(const _Float16* __restrict__ CH,
                                             const int* __restrict__ edges,
                                             _Float16* __restrict__ ES1s, int E){
    int wave = threadIdx.x >> 6, lane = threadIdx.x & 63;
    int e = blockIdx.x*4 + wave;
    if (e >= E) return;
    int rid = edges[(size_t)e*16 + (lane & 15)];   // lane s holds node id s (dup x4)
    float s0 = 0.f, s1 = 0.f;
    #pragma unroll
    for (int s=0;s<16;++s){
        int idx = __shfl(rid, s, 64);
        half2v v = *(const half2v*)(CH + (size_t)idx*128 + lane*2);
        float f0 = (float)v[0], f1 = (float)v[1];
        s0 += f0*f0; s1 += f1*f1;
    }
    half2v o; o[0] = (_Float16)(s0*INV15); o[1] = (_Float16)(s1*INV15);
    *(half2v*)(ES1s + (size_t)e*128 + lane*2) = o;
}

// Fused layer-1 (R6 structure + packed-f16 accumulation): gather (half-wave/node,
// zero-row padded maskless unroll-4, pk_add_f16 accumulate) -> LDS -> dot2 gemm.
__global__ __launch_bounds__(256) void fused_l1(
    const _Float16* __restrict__ CH, const _Float16* __restrict__ ES1s,
    const int* __restrict__ cnt, const unsigned short* __restrict__ lists,
    const float* __restrict__ W1, const float* __restrict__ b1,
    _Float16* __restrict__ X, int N, int EZERO){
    __shared__ _Float16 snw[8*128];
    int tid = threadIdx.x;
    int wave = tid >> 6, lane = tid & 63;

    int q = lane >> 4, h = lane & 15;
    half2v w2[16];
    #pragma unroll
    for (int i=0;i<16;++i){
        w2[i][0] = (_Float16)W1[(q*32+2*i  )*16 + h];
        w2[i][1] = (_Float16)W1[(q*32+2*i+1)*16 + h];
    }
    const half2v ones = {(_Float16)1.f, (_Float16)1.f};
    float bv = b1[h];

    int hw = tid >> 5;        // half-wave id 0..7
    int k32 = tid & 31;
    int dq = k32 * 4;
    int nb = blockIdx.x * 8;

    const _Float16 i15 = (_Float16)INV15;
    const half4v i15v = {i15, i15, i15, i15};
    const half4v z4 = {(_Float16)0.f,(_Float16)0.f,(_Float16)0.f,(_Float16)0.f};

    // ---- phase 1: gather node nb+hw ----
    int n = nb + hw;
    if (n < N){
        int len = cnt[n]; if (len > CAP) len = CAP;
        int myid = (int)lists[(size_t)n*CAP + k32];
        myid = (k32 < len) ? myid : EZERO;      // pad -> zeros row (exact 0 contrib)

        half4v hv = *(const half4v*)(CH + (size_t)n*128 + dq);
        half4v p16 = (hv * hv) * i15v;

        half4v acc = z4;                        // f16 packed accumulate (<=32 adds, safe)
        for (int k0=0;k0<len;k0+=4){
            int e0 = __shfl(myid, k0,   32);
            int e1 = __shfl(myid, k0+1, 32);
            int e2 = __shfl(myid, k0+2, 32);
            int e3 = __shfl(myid, k0+3, 32);
            half4v v0 = *(const half4v*)(ES1s + (size_t)e0*128 + dq);
            half4v v1 = *(const half4v*)(ES1s + (size_t)e1*128 + dq);
            half4v v2 = *(const half4v*)(ES1s + (size_t)e2*128 + dq);
            half4v v3 = *(const half4v*)(ES1s + (size_t)e3*128 + dq);
            acc = acc + __builtin_elementwise_sqrt(__builtin_elementwise_max(v0 - p16, z4));
            acc = acc + __builtin_elementwise_sqrt(__builtin_elementwise_max(v1 - p16, z4));
            acc = acc + __builtin_elementwise_sqrt(__builtin_elementwise_max(v2 - p16, z4));
            acc = acc + __builtin_elementwise_sqrt(__builtin_elementwise_max(v3 - p16, z4));
        }
        *(half4v*)&snw[hw*128 + dq] = hv + acc;
    }
    __syncthreads();

    // ---- phase 2: wave handles nodes nb+wave*2 .. +1, dot2 gemm ----
    #pragma unroll
    for (int r=0;r<2;++r){
        int nl = wave*2 + r;
        int n2 = nb + nl;
        if (n2 >= N) continue;
        float acc = 0.f, rs = 0.f;
        #pragma unroll
        for (int j=0;j<8;++j){
            half4v v = *(const half4v*)&snw[nl*128 + q*32 + j*4];
            half2v lo = {v[0], v[1]}, hi = {v[2], v[3]};
            acc = __builtin_amdgcn_fdot2(lo, w2[j*2  ], acc, false);
            acc = __builtin_amdgcn_fdot2(hi, w2[j*2+1], acc, false);
            rs  = __builtin_amdgcn_fdot2(lo, ones, rs, false);
            rs  = __builtin_amdgcn_fdot2(hi, ones, rs, false);
        }
        acc += __shfl_xor(acc, 16, 64);
        rs  += __shfl_xor(rs , 16, 64);
        acc += __shfl_xor(acc, 32, 64);
        rs  += __shfl_xor(rs , 32, 64);
        if (q == 0){
            float o = acc * __builtin_amdgcn_rcpf(rs) + bv;
            X[(size_t)n2*16 + h] = (_Float16)fmaxf(o, 0.f);
        }
    }
}

// ES2s[e][d] = (1/15) * sum_s clip(X[idx_s][d])^2, f32. Thread per (edge, 2 dims).
// (R5's version.)
__global__ __launch_bounds__(256) void es_l2(const _Float16* __restrict__ X,
                                             const int* __restrict__ edges,
                                             float* __restrict__ ES2s, int E){
    int t = blockIdx.x*256 + threadIdx.x;
    int e = t >> 3, dd2 = (t & 7)*2;
    if (e >= E) return;
    const int* row = edges + (size_t)e*16;
    float s0 = 0.f, s1 = 0.f;
    #pragma unroll
    for (int s=0;s<16;++s){
        half2v v = *(const half2v*)(X + (size_t)row[s]*16 + dd2);
        float f0 = clipv((float)v[0]), f1 = clipv((float)v[1]);
        s0 += f0*f0; s1 += f1*f1;
    }
    ES2s[(size_t)e*16 + dd2]     = s0*INV15;
    ES2s[(size_t)e*16 + dd2 + 1] = s1*INV15;
}

// Layer-2 fused node update: thread-per-node, f32 core, masked unroll-2 (R5's version).
__global__ __launch_bounds__(256) void node_l2(
    const _Float16* __restrict__ X, const float* __restrict__ ES2s,
    const int* __restrict__ cnt, const unsigned short* __restrict__ lists,
    const float* __restrict__ W2, const float* __restrict__ b2,
    float* __restrict__ out, int N){
    __shared__ float sW[640];
    __shared__ float sb[40];
    for (int i=threadIdx.x;i<640;i+=256) sW[i] = W2[i];
    if (threadIdx.x < 40) sb[threadIdx.x] = b2[threadIdx.x];
    __syncthreads();
    int n = blockIdx.x*256 + threadIdx.x;
    if (n >= N) return;
    float xc[16], ps[16], ad[16];
    const half8v* xr = (const half8v*)(X + (size_t)n*16);
    half8v x0 = xr[0], x1 = xr[1];
    #pragma unroll
    for (int d=0;d<8;++d){
        float v = clipv((float)x0[d]);
        xc[d]=v; ps[d]=v*v*INV15; ad[d]=0.f;
    }
    #pragma unroll
    for (int d=0;d<8;++d){
        float v = clipv((float)x1[d]);
        xc[8+d]=v; ps[8+d]=v*v*INV15; ad[8+d]=0.f;
    }
    int len = cnt[n]; if (len > CAP) len = CAP;
    const unsigned short* lrow = lists + (size_t)n*CAP;
    for (int k0=0;k0<len;k0+=2){
        int e0 = lrow[k0];
        int e1 = (k0+1 < len) ? lrow[k0+1] : e0;
        bool m1 = (k0+1 < len);
        const float4* r0 = (const float4*)(ES2s + (size_t)e0*16);
        const float4* r1 = (const float4*)(ES2s + (size_t)e1*16);
        #pragma unroll
        for (int j=0;j<4;++j){
            float4 ea = r0[j], eb = r1[j];
            ad[j*4+0] += rsqrt_arg(ea.x - ps[j*4+0]);
            ad[j*4+1] += rsqrt_arg(ea.y - ps[j*4+1]);
            ad[j*4+2] += rsqrt_arg(ea.z - ps[j*4+2]);
            ad[j*4+3] += rsqrt_arg(ea.w - ps[j*4+3]);
            ad[j*4+0] += m1 ? rsqrt_arg(eb.x - ps[j*4+0]) : 0.f;
            ad[j*4+1] += m1 ? rsqrt_arg(eb.y - ps[j*4+1]) : 0.f;
            ad[j*4+2] += m1 ? rsqrt_arg(eb.z - ps[j*4+2]) : 0.f;
            ad[j*4+3] += m1 ? rsqrt_arg(eb.w - ps[j*4+3]) : 0.f;
        }
    }
    float rs = 0.f;
    float nw[16];
    #pragma unroll
    for (int d=0;d<16;++d){ nw[d] = xc[d] + ad[d]; rs += nw[d]; }
    float rinv = __builtin_amdgcn_rcpf(rs);
    float acc[40];
    #pragma unroll
    for (int c=0;c<40;++c) acc[c] = 0.f;
    #pragma unroll
    for (int d=0;d<16;++d){
        float v = nw[d];
        #pragma unroll
        for (int c=0;c<40;++c) acc[c] += v * sW[d*40+c];
    }
    float4 ob[10];
    #pragma unroll
    for (int c=0;c<40;++c) ((float*)ob)[c] = rinv*acc[c] + sb[c];
    float4* op = (float4*)(out + (size_t)n*40);
    #pragma unroll
    for (int j=0;j<10;++j) op[j] = ob[j];
}

extern "C" void kernel_launch(void* const* d_in, const int* in_sizes, int n_in,
                              void* d_out, int out_size, void* d_ws, size_t ws_size,
                              hipStream_t stream){
    (void)n_in; (void)out_size; (void)ws_size;
    const float* H  = (const float*)d_in[0];
    const float* W1 = (const float*)d_in[1];
    const float* b1 = (const float*)d_in[2];
    const float* W2 = (const float*)d_in[3];
    const float* b2 = (const float*)d_in[4];
    const int* edges = (const int*)d_in[5];
    float* out = (float*)d_out;

    const int N = in_sizes[0] / 128;   // 200000
    const int E = in_sizes[5] / 16;    // 40000
    const int total = E * 16;          // 640000
    const int total8 = N * 128 / 8;    // 3.2M

    char* ws = (char*)d_ws;
    size_t off = 0;
    // region A: CH (dead after fused_l1) -> reused for ES2s (f32, 2.56 MB)
    _Float16* CH  = (_Float16*)(ws + off);
    float* ES2s   = (float*)(ws + off);
    off += (size_t)N*128*sizeof(_Float16);                  // 51.20 MB
    _Float16* ES1s = (_Float16*)(ws + off); off += (size_t)(E+1)*128*sizeof(_Float16); // 10.24 MB
    _Float16* X    = (_Float16*)(ws + off); off += (size_t)N*16*sizeof(_Float16);      //  6.40 MB
    int* cnt = (int*)(ws + off); off += (size_t)N*sizeof(int);                         //  0.80 MB
    unsigned short* lists = (unsigned short*)(ws + off);
    off += (size_t)N*CAP*sizeof(unsigned short);                                       // 12.80 MB

    hipMemsetAsync(cnt, 0, (size_t)N*sizeof(int), stream);
    hipMemsetAsync(ES1s + (size_t)E*128, 0, 128*sizeof(_Float16), stream);  // zeros row
    ch_stream<<<2048, 256, 0, stream>>>(H, CH, total8);
    build_lists<<<(total+255)/256, 256, 0, stream>>>(edges, cnt, lists, total);
    es_l1<<<(E+3)/4, 256, 0, stream>>>(CH, edges, ES1s, E);
    fused_l1<<<(N+7)/8, 256, 0, stream>>>(CH, ES1s, cnt, lists, W1, b1, X, N, E);
    // CH dead from here; ES2s (f32) overwrites region A
    es_l2<<<(E*8+255)/256, 256, 0, stream>>>(X, edges, ES2s, E);
    node_l2<<<(N+255)/256, 256, 0, stream>>>(X, ES2s, cnt, lists, W2, b2, out, N);
}

// Round 11
// 196.066 us; speedup vs baseline: 1.0842x; 1.0715x over previous
//
#include <hip/hip_runtime.h>

#define MIN_V 1e-7f
#define MAX_V 10.0f
#define INV15 (1.0f/15.0f)
#define CAP 32

typedef _Float16 half2v __attribute__((ext_vector_type(2)));
typedef _Float16 half4v __attribute__((ext_vector_type(4)));
typedef _Float16 half8v __attribute__((ext_vector_type(8)));

static __device__ __forceinline__ float clipv(float v){
    return fminf(fmaxf(v, MIN_V), MAX_V);
}
static __device__ __forceinline__ half2v shflx1(half2v v){
    int i = __builtin_bit_cast(int, v);
    i = __shfl_xor(i, 1, 64);
    return __builtin_bit_cast(half2v, i);
}

// Pure streaming pass: CH[i] = fp16(clip(H[i])), grid-stride, 8 elems/thread/iter
__global__ __launch_bounds__(256) void ch_stream(const float* __restrict__ H,
                                                 _Float16* __restrict__ CH, int total8){
    int stride = gridDim.x*256;
    for (int i = blockIdx.x*256 + threadIdx.x; i < total8; i += stride){
        const float4* p = (const float4*)(H + (size_t)i*8);
        float4 a = p[0], b = p[1];
        half8v o;
        o[0]=(_Float16)clipv(a.x); o[1]=(_Float16)clipv(a.y);
        o[2]=(_Float16)clipv(a.z); o[3]=(_Float16)clipv(a.w);
        o[4]=(_Float16)clipv(b.x); o[5]=(_Float16)clipv(b.y);
        o[6]=(_Float16)clipv(b.z); o[7]=(_Float16)clipv(b.w);
        *(half8v*)(CH + (size_t)i*8) = o;
    }
}

// node -> edge incidence lists (ushort edge ids; one 64B line per node)
__global__ void build_lists(const int* __restrict__ edges, int* __restrict__ cnt,
                            unsigned short* __restrict__ lists, int total){
    int i = blockIdx.x*256 + threadIdx.x;
    if (i >= total) return;
    int node = edges[i];
    int p = atomicAdd(&cnt[node], 1);
    if (p < CAP) lists[(size_t)node*CAP + p] = (unsigned short)(i >> 4);
}

// ES1s[e][d] = (1/15) * sum_s CH[idx_s][d]^2, fp16.
// 16 lanes per edge, half8v (16-B) loads; ids preloaded one-per-lane + shfl broadcast.
__global__ __launch_bounds__(256) void es_l1(const _Float16* __restrict__ CH,
                                             const int* __restrict__ edges,
                                             _Float16* __restrict__ ES1s, int E){
    int tid = threadIdx.x;
    int sub = tid & 15;
    int e = blockIdx.x*16 + (tid >> 4);
    if (e >= E) return;
    int nid = edges[(size_t)e*16 + sub];   // lane s (within 16-group) holds node id s
    float s[8];
    #pragma unroll
    for (int j=0;j<8;++j) s[j] = 0.f;
    #pragma unroll
    for (int t=0;t<16;++t){
        int idx = __shfl(nid, t, 16);      // broadcast within the 16-lane group
        half8v v = *(const half8v*)(CH + (size_t)idx*128 + sub*8);
        #pragma unroll
        for (int j=0;j<8;++j){ float f = (float)v[j]; s[j] += f*f; }
    }
    half8v o;
    #pragma unroll
    for (int j=0;j<8;++j) o[j] = (_Float16)(s[j]*INV15);
    *(half8v*)(ES1s + (size_t)e*128 + sub*8) = o;
}

// Fused layer-1 (R10's best): gather (half-wave/node, zero-row padded maskless
// unroll-4, pk_add_f16 accumulate) -> LDS -> dot2 gemm.
__global__ __launch_bounds__(256) void fused_l1(
    const _Float16* __restrict__ CH, const _Float16* __restrict__ ES1s,
    const int* __restrict__ cnt, const unsigned short* __restrict__ lists,
    const float* __restrict__ W1, const float* __restrict__ b1,
    _Float16* __restrict__ X, int N, int EZERO){
    __shared__ _Float16 snw[8*128];
    int tid = threadIdx.x;
    int wave = tid >> 6, lane = tid & 63;

    int q = lane >> 4, h = lane & 15;
    half2v w2[16];
    #pragma unroll
    for (int i=0;i<16;++i){
        w2[i][0] = (_Float16)W1[(q*32+2*i  )*16 + h];
        w2[i][1] = (_Float16)W1[(q*32+2*i+1)*16 + h];
    }
    const half2v ones = {(_Float16)1.f, (_Float16)1.f};
    float bv = b1[h];

    int hw = tid >> 5;        // half-wave id 0..7
    int k32 = tid & 31;
    int dq = k32 * 4;
    int nb = blockIdx.x * 8;

    const _Float16 i15 = (_Float16)INV15;
    const half4v i15v = {i15, i15, i15, i15};
    const half4v z4 = {(_Float16)0.f,(_Float16)0.f,(_Float16)0.f,(_Float16)0.f};

    // ---- phase 1: gather node nb+hw ----
    int n = nb + hw;
    if (n < N){
        int len = cnt[n]; if (len > CAP) len = CAP;
        int myid = (int)lists[(size_t)n*CAP + k32];
        myid = (k32 < len) ? myid : EZERO;      // pad -> zeros row (exact 0 contrib)

        half4v hv = *(const half4v*)(CH + (size_t)n*128 + dq);
        half4v p16 = (hv * hv) * i15v;

        half4v acc = z4;                        // f16 packed accumulate (<=32 adds, safe)
        for (int k0=0;k0<len;k0+=4){
            int e0 = __shfl(myid, k0,   32);
            int e1 = __shfl(myid, k0+1, 32);
            int e2 = __shfl(myid, k0+2, 32);
            int e3 = __shfl(myid, k0+3, 32);
            half4v v0 = *(const half4v*)(ES1s + (size_t)e0*128 + dq);
            half4v v1 = *(const half4v*)(ES1s + (size_t)e1*128 + dq);
            half4v v2 = *(const half4v*)(ES1s + (size_t)e2*128 + dq);
            half4v v3 = *(const half4v*)(ES1s + (size_t)e3*128 + dq);
            acc = acc + __builtin_elementwise_sqrt(__builtin_elementwise_max(v0 - p16, z4));
            acc = acc + __builtin_elementwise_sqrt(__builtin_elementwise_max(v1 - p16, z4));
            acc = acc + __builtin_elementwise_sqrt(__builtin_elementwise_max(v2 - p16, z4));
            acc = acc + __builtin_elementwise_sqrt(__builtin_elementwise_max(v3 - p16, z4));
        }
        *(half4v*)&snw[hw*128 + dq] = hv + acc;
    }
    __syncthreads();

    // ---- phase 2: wave handles nodes nb+wave*2 .. +1, dot2 gemm ----
    #pragma unroll
    for (int r=0;r<2;++r){
        int nl = wave*2 + r;
        int n2 = nb + nl;
        if (n2 >= N) continue;
        float acc = 0.f, rs = 0.f;
        #pragma unroll
        for (int j=0;j<8;++j){
            half4v v = *(const half4v*)&snw[nl*128 + q*32 + j*4];
            half2v lo = {v[0], v[1]}, hi = {v[2], v[3]};
            acc = __builtin_amdgcn_fdot2(lo, w2[j*2  ], acc, false);
            acc = __builtin_amdgcn_fdot2(hi, w2[j*2+1], acc, false);
            rs  = __builtin_amdgcn_fdot2(lo, ones, rs, false);
            rs  = __builtin_amdgcn_fdot2(hi, ones, rs, false);
        }
        acc += __shfl_xor(acc, 16, 64);
        rs  += __shfl_xor(rs , 16, 64);
        acc += __shfl_xor(acc, 32, 64);
        rs  += __shfl_xor(rs , 32, 64);
        if (q == 0){
            float o = acc * __builtin_amdgcn_rcpf(rs) + bv;
            X[(size_t)n2*16 + h] = (_Float16)fmaxf(o, 0.f);
        }
    }
}

// ES2s[e][d] = (1/15) * sum_s clipfloor(X[idx_s][d])^2, fp16. Thread = (edge, 4 dims).
// (X <= 0.5 provably, so the upper clip at 10 is a no-op; only the 1e-7 floor matters.)
__global__ __launch_bounds__(256) void es_l2(const _Float16* __restrict__ X,
                                             const int* __restrict__ edges,
                                             _Float16* __restrict__ ES2s, int E){
    int t = blockIdx.x*256 + threadIdx.x;
    int e = t >> 2, dq = (t & 3)*4;
    if (e >= E) return;
    const int* row = edges + (size_t)e*16;
    const _Float16 c7 = (_Float16)1e-7f;
    const half4v c7v = {c7, c7, c7, c7};
    float s0=0.f, s1=0.f, s2=0.f, s3=0.f;
    #pragma unroll
    for (int s=0;s<16;++s){
        half4v v = *(const half4v*)(X + (size_t)row[s]*16 + dq);
        v = __builtin_elementwise_max(v, c7v);
        float f0=(float)v[0], f1=(float)v[1], f2=(float)v[2], f3=(float)v[3];
        s0 += f0*f0; s1 += f1*f1; s2 += f2*f2; s3 += f3*f3;
    }
    half4v o;
    o[0]=(_Float16)(s0*INV15); o[1]=(_Float16)(s1*INV15);
    o[2]=(_Float16)(s2*INV15); o[3]=(_Float16)(s3*INV15);
    *(half4v*)(ES2s + (size_t)e*16 + dq) = o;
}

// Layer-2 node update: TWO threads per node (p = lane&1 owns 8 dims / 20 cols).
// Halved serial gather chain, 2x waves; register exchange via shfl_xor(1).
__global__ __launch_bounds__(256) void node_l2(
    const _Float16* __restrict__ X, const _Float16* __restrict__ ES2s,
    const int* __restrict__ cnt, const unsigned short* __restrict__ lists,
    const float* __restrict__ W2, const float* __restrict__ b2,
    float* __restrict__ out, int N, int EZERO){
    __shared__ half2v sW2h[8*40];
    __shared__ float sb[40];
    for (int i=threadIdx.x;i<320;i+=256){
        int d2 = i/40, c = i - d2*40;
        half2v wp;
        wp[0] = (_Float16)W2[(2*d2  )*40 + c];
        wp[1] = (_Float16)W2[(2*d2+1)*40 + c];
        sW2h[i] = wp;
    }
    if (threadIdx.x < 40) sb[threadIdx.x] = b2[threadIdx.x];
    __syncthreads();
    int t = blockIdx.x*256 + threadIdx.x;
    int n = t >> 1, p = t & 1;
    if (n >= N) return;

    const _Float16 c7 = (_Float16)1e-7f;
    const half8v c7v = {c7,c7,c7,c7,c7,c7,c7,c7};
    const half8v z8 = {(_Float16)0.f,(_Float16)0.f,(_Float16)0.f,(_Float16)0.f,
                       (_Float16)0.f,(_Float16)0.f,(_Float16)0.f,(_Float16)0.f};
    const _Float16 i15 = (_Float16)INV15;
    const half8v i15v = {i15,i15,i15,i15,i15,i15,i15,i15};

    half8v xh = *(const half8v*)(X + (size_t)n*16 + p*8);
    xh = __builtin_elementwise_max(xh, c7v);
    half8v ps = (xh*xh)*i15v;

    float xc[8], ad[8];
    #pragma unroll
    for (int d=0;d<8;++d){ xc[d]=(float)xh[d]; ad[d]=0.f; }

    int len = cnt[n]; if (len > CAP) len = CAP;
    const unsigned short* lrow = lists + (size_t)n*CAP;
    for (int k0=0;k0<len;k0+=4){
        int e0 = (int)lrow[k0];
        int e1 = (k0+1 < len) ? (int)lrow[k0+1] : EZERO;
        int e2 = (k0+2 < len) ? (int)lrow[k0+2] : EZERO;
        int e3 = (k0+3 < len) ? (int)lrow[k0+3] : EZERO;
        half8v r0 = *(const half8v*)(ES2s + (size_t)e0*16 + p*8);
        half8v r1 = *(const half8v*)(ES2s + (size_t)e1*16 + p*8);
        half8v r2 = *(const half8v*)(ES2s + (size_t)e2*16 + p*8);
        half8v r3 = *(const half8v*)(ES2s + (size_t)e3*16 + p*8);
        half8v s0 = __builtin_elementwise_sqrt(__builtin_elementwise_max(r0-ps, z8));
        half8v s1 = __builtin_elementwise_sqrt(__builtin_elementwise_max(r1-ps, z8));
        half8v s2 = __builtin_elementwise_sqrt(__builtin_elementwise_max(r2-ps, z8));
        half8v s3 = __builtin_elementwise_sqrt(__builtin_elementwise_max(r3-ps, z8));
        #pragma unroll
        for (int d=0;d<8;++d)
            ad[d] += ((float)s0[d] + (float)s1[d]) + ((float)s2[d] + (float)s3[d]);
    }
    float rsl = 0.f;
    float nw[8];
    #pragma unroll
    for (int d=0;d<8;++d){ nw[d] = xc[d] + ad[d]; rsl += nw[d]; }
    float rs = rsl + __shfl_xor(rsl, 1, 64);
    float rinv = __builtin_amdgcn_rcpf(rs);

    half2v mine[4], oth[4];
    #pragma unroll
    for (int i=0;i<4;++i){
        mine[i][0] = (_Float16)nw[2*i];
        mine[i][1] = (_Float16)nw[2*i+1];
        oth[i] = shflx1(mine[i]);
    }
    half2v all8[8];
    #pragma unroll
    for (int i=0;i<4;++i){
        all8[4*p + i]     = mine[i];
        all8[4*(1-p) + i] = oth[i];
    }

    float ob[20];
    #pragma unroll
    for (int c=0;c<20;++c){
        int col = p*20 + c;
        float acc = 0.f;
        #pragma unroll
        for (int d2=0;d2<8;++d2)
            acc = __builtin_amdgcn_fdot2(all8[d2], sW2h[d2*40+col], acc, false);
        ob[c] = rinv*acc + sb[col];
    }
    float4* op = (float4*)(out + (size_t)n*40 + p*20);
    #pragma unroll
    for (int j=0;j<5;++j) op[j] = ((float4*)ob)[j];
}

extern "C" void kernel_launch(void* const* d_in, const int* in_sizes, int n_in,
                              void* d_out, int out_size, void* d_ws, size_t ws_size,
                              hipStream_t stream){
    (void)n_in; (void)out_size; (void)ws_size;
    const float* H  = (const float*)d_in[0];
    const float* W1 = (const float*)d_in[1];
    const float* b1 = (const float*)d_in[2];
    const float* W2 = (const float*)d_in[3];
    const float* b2 = (const float*)d_in[4];
    const int* edges = (const int*)d_in[5];
    float* out = (float*)d_out;

    const int N = in_sizes[0] / 128;   // 200000
    const int E = in_sizes[5] / 16;    // 40000
    const int total = E * 16;          // 640000
    const int total8 = N * 128 / 8;    // 3.2M

    char* ws = (char*)d_ws;
    size_t off = 0;
    // region A: CH (dead after fused_l1) -> reused for ES2s (fp16, (E+1)x32B)
    _Float16* CH   = (_Float16*)(ws + off);
    _Float16* ES2s = (_Float16*)(ws + off);
    off += (size_t)N*128*sizeof(_Float16);                  // 51.20 MB
    _Float16* ES1s = (_Float16*)(ws + off); off += (size_t)(E+1)*128*sizeof(_Float16); // 10.24 MB
    _Float16* X    = (_Float16*)(ws + off); off += (size_t)N*16*sizeof(_Float16);      //  6.40 MB
    int* cnt = (int*)(ws + off); off += (size_t)N*sizeof(int);                         //  0.80 MB
    unsigned short* lists = (unsigned short*)(ws + off);
    off += (size_t)N*CAP*sizeof(unsigned short);                                       // 12.80 MB

    hipMemsetAsync(cnt, 0, (size_t)N*sizeof(int), stream);
    hipMemsetAsync(ES1s + (size_t)E*128, 0, 128*sizeof(_Float16), stream);  // zeros row
    ch_stream<<<2048, 256, 0, stream>>>(H, CH, total8);
    build_lists<<<(total+255)/256, 256, 0, stream>>>(edges, cnt, lists, total);
    es_l1<<<(E+15)/16, 256, 0, stream>>>(CH, edges, ES1s, E);
    fused_l1<<<(N+7)/8, 256, 0, stream>>>(CH, ES1s, cnt, lists, W1, b1, X, N, E);
    // CH dead from here; ES2s (fp16) overwrites region A
    hipMemsetAsync(ES2s + (size_t)E*16, 0, 16*sizeof(_Float16), stream);    // zeros row
    es_l2<<<(E*4+255)/256, 256, 0, stream>>>(X, edges, ES2s, E);
    node_l2<<<(N*2+255)/256, 256, 0, stream>>>(X, ES2s, cnt, lists, W2, b2, out, N, E);
}